// Round 2
// baseline (55.105 us; speedup 1.0000x reference)
//
#include <hip/hip_runtime.h>

// out[b] = dot(x[b,:], W[actions[b],:]) + bias[actions[b]]        (is_global==0)
// out[b] = max_p ( dot(x[b,:], W[p,:]) + bias[p] )                (is_global!=0)
//
// B=65536, C=1024, P=4, fp32. Memory-bound: 256 MiB x-read dominates.
// x is streamed (read exactly once) -> non-temporal loads to skip cache alloc.

#define BLOCK 256
#define WAVES_PER_BLOCK (BLOCK / 64)
#define MAX_P 8
#define MAX_WLDS 4096   // P*C floats staged in LDS (P=4, C=1024 -> 16 KiB)

typedef float f32x4 __attribute__((ext_vector_type(4)));

__global__ __launch_bounds__(BLOCK, 4) void ranker_kernel(
    const float* __restrict__ x,        // [B, C]
    const float* __restrict__ W,        // [P, C]
    const float* __restrict__ bias,     // [P]
    const int*   __restrict__ actions,  // [B]
    const int*   __restrict__ is_global_p,
    float* __restrict__ out,            // [B]
    int B, int C, int P)
{
    __shared__ float Wlds[MAX_WLDS];
    __shared__ float blds[MAX_P];

    const int tid = threadIdx.x;

    // Stage W into LDS (vectorized, cooperative). P*C is a multiple of 4.
    const int nvec = (P * C) >> 2;
    const f32x4* Wv = reinterpret_cast<const f32x4*>(W);
    f32x4* Wldsv = reinterpret_cast<f32x4*>(Wlds);
    for (int i = tid; i < nvec; i += BLOCK) Wldsv[i] = Wv[i];
    if (tid < P) blds[tid] = bias[tid];
    __syncthreads();

    const int lane  = tid & 63;
    const int wid   = tid >> 6;
    const int gwave = blockIdx.x * WAVES_PER_BLOCK + wid;
    const int nwav  = gridDim.x * WAVES_PER_BLOCK;
    const int ig    = *is_global_p;     // wave-uniform scalar
    const int cvec  = C >> 2;           // float4s per row (256 for C=1024)

    if (!ig) {
        for (int row = gwave; row < B; row += nwav) {
            const f32x4* xr = reinterpret_cast<const f32x4*>(x) + (size_t)row * cvec;
            const int a = actions[row];
            const f32x4* wr = reinterpret_cast<const f32x4*>(Wlds + a * C);
            float s = 0.f;
            #pragma unroll 4
            for (int j = lane; j < cvec; j += 64) {
                f32x4 xv = __builtin_nontemporal_load(xr + j);
                f32x4 wv = wr[j];
                s += xv.x * wv.x + xv.y * wv.y + xv.z * wv.z + xv.w * wv.w;
            }
            #pragma unroll
            for (int off = 32; off > 0; off >>= 1)
                s += __shfl_down(s, off, 64);
            if (lane == 0) __builtin_nontemporal_store(s + blds[a], out + row);
        }
    } else {
        for (int row = gwave; row < B; row += nwav) {
            const f32x4* xr = reinterpret_cast<const f32x4*>(x) + (size_t)row * cvec;
            float s0 = 0.f, s1 = 0.f, s2 = 0.f, s3 = 0.f;
            #pragma unroll 4
            for (int j = lane; j < cvec; j += 64) {
                f32x4 xv = __builtin_nontemporal_load(xr + j);
                f32x4 w0 = reinterpret_cast<const f32x4*>(Wlds + 0 * C)[j];
                f32x4 w1 = reinterpret_cast<const f32x4*>(Wlds + 1 * C)[j];
                f32x4 w2 = reinterpret_cast<const f32x4*>(Wlds + 2 * C)[j];
                f32x4 w3 = reinterpret_cast<const f32x4*>(Wlds + 3 * C)[j];
                s0 += xv.x * w0.x + xv.y * w0.y + xv.z * w0.z + xv.w * w0.w;
                s1 += xv.x * w1.x + xv.y * w1.y + xv.z * w1.z + xv.w * w1.w;
                s2 += xv.x * w2.x + xv.y * w2.y + xv.z * w2.z + xv.w * w2.w;
                s3 += xv.x * w3.x + xv.y * w3.y + xv.z * w3.z + xv.w * w3.w;
            }
            #pragma unroll
            for (int off = 32; off > 0; off >>= 1) {
                s0 += __shfl_down(s0, off, 64);
                s1 += __shfl_down(s1, off, 64);
                s2 += __shfl_down(s2, off, 64);
                s3 += __shfl_down(s3, off, 64);
            }
            if (lane == 0) {
                float m = s0 + blds[0];
                m = fmaxf(m, s1 + blds[1]);
                m = fmaxf(m, s2 + blds[2]);
                m = fmaxf(m, s3 + blds[3]);
                __builtin_nontemporal_store(m, out + row);
            }
        }
    }
}

extern "C" void kernel_launch(void* const* d_in, const int* in_sizes, int n_in,
                              void* d_out, int out_size, void* d_ws, size_t ws_size,
                              hipStream_t stream) {
    const float* x        = (const float*)d_in[0];
    const float* W        = (const float*)d_in[1];
    const float* bias     = (const float*)d_in[2];
    const int*   actions  = (const int*)d_in[3];
    const int*   is_glob  = (const int*)d_in[4];
    float* out            = (float*)d_out;

    const int B = in_sizes[3];            // actions count
    const int P = in_sizes[2];            // bias count
    const int C = in_sizes[0] / B;        // 1024

    // Memory-bound: cap grid at ~2048 blocks, grid-stride the rows.
    int blocks = (B + WAVES_PER_BLOCK - 1) / WAVES_PER_BLOCK;
    if (blocks > 2048) blocks = 2048;

    ranker_kernel<<<blocks, BLOCK, 0, stream>>>(x, W, bias, actions, is_glob,
                                                out, B, C, P);
}

// Round 3
// 45.396 us; speedup vs baseline: 1.2139x; 1.2139x over previous
//
#include <hip/hip_runtime.h>

// out[b] = dot(x[b,:], W[actions[b],:]) + bias[actions[b]]        (is_global==0)
// out[b] = max_p ( dot(x[b,:], W[p,:]) + bias[p] )                (is_global!=0)
//
// B=65536, C=1024, P=4, fp32. Memory-bound: 256 MiB x-read dominates.
// R2 lesson: __builtin_nontemporal_load REGRESSED (46->55us) on gfx950 - reverted.
// R3: 2-row interleave per wave iteration for deeper MLP across the shfl chain.

#define BLOCK 256
#define WAVES_PER_BLOCK (BLOCK / 64)
#define MAX_P 8
#define MAX_WLDS 4096   // P*C floats staged in LDS (P=4, C=1024 -> 16 KiB)

typedef float f32x4 __attribute__((ext_vector_type(4)));

__device__ __forceinline__ float dot4(const f32x4 a, const f32x4 b) {
    return a.x * b.x + a.y * b.y + a.z * b.z + a.w * b.w;
}

__global__ __launch_bounds__(BLOCK, 4) void ranker_kernel(
    const float* __restrict__ x,        // [B, C]
    const float* __restrict__ W,        // [P, C]
    const float* __restrict__ bias,     // [P]
    const int*   __restrict__ actions,  // [B]
    const int*   __restrict__ is_global_p,
    float* __restrict__ out,            // [B]
    int B, int C, int P)
{
    __shared__ float Wlds[MAX_WLDS];
    __shared__ float blds[MAX_P];

    const int tid = threadIdx.x;

    // Stage W into LDS (vectorized, cooperative). P*C is a multiple of 4.
    const int nvec = (P * C) >> 2;
    const f32x4* Wv = reinterpret_cast<const f32x4*>(W);
    f32x4* Wldsv = reinterpret_cast<f32x4*>(Wlds);
    for (int i = tid; i < nvec; i += BLOCK) Wldsv[i] = Wv[i];
    if (tid < P) blds[tid] = bias[tid];
    __syncthreads();

    const int lane  = tid & 63;
    const int wid   = tid >> 6;
    const int gwave = blockIdx.x * WAVES_PER_BLOCK + wid;
    const int nwav  = gridDim.x * WAVES_PER_BLOCK;
    const int ig    = *is_global_p;     // wave-uniform scalar
    const int cvec  = C >> 2;           // float4s per row (256 for C=1024)

    if (!ig) {
        int row = gwave;
        // Paired rows: issue both rows' load streams before either reduction.
        for (; row + nwav < B; row += 2 * nwav) {
            const int r0 = row, r1 = row + nwav;
            const f32x4* xr0 = reinterpret_cast<const f32x4*>(x) + (size_t)r0 * cvec;
            const f32x4* xr1 = reinterpret_cast<const f32x4*>(x) + (size_t)r1 * cvec;
            const int a0 = actions[r0];
            const int a1 = actions[r1];
            const f32x4* wr0 = reinterpret_cast<const f32x4*>(Wlds + a0 * C);
            const f32x4* wr1 = reinterpret_cast<const f32x4*>(Wlds + a1 * C);
            float s0 = 0.f, s1 = 0.f;
            #pragma unroll 4
            for (int j = lane; j < cvec; j += 64) {
                f32x4 xv0 = xr0[j];
                f32x4 xv1 = xr1[j];
                s0 += dot4(xv0, wr0[j]);
                s1 += dot4(xv1, wr1[j]);
            }
            #pragma unroll
            for (int off = 32; off > 0; off >>= 1) {
                s0 += __shfl_down(s0, off, 64);
                s1 += __shfl_down(s1, off, 64);
            }
            if (lane == 0) {
                out[r0] = s0 + blds[a0];
                out[r1] = s1 + blds[a1];
            }
        }
        // Tail (if rows-per-wave is odd).
        for (; row < B; row += nwav) {
            const f32x4* xr = reinterpret_cast<const f32x4*>(x) + (size_t)row * cvec;
            const int a = actions[row];
            const f32x4* wr = reinterpret_cast<const f32x4*>(Wlds + a * C);
            float s = 0.f;
            #pragma unroll 4
            for (int j = lane; j < cvec; j += 64)
                s += dot4(xr[j], wr[j]);
            #pragma unroll
            for (int off = 32; off > 0; off >>= 1)
                s += __shfl_down(s, off, 64);
            if (lane == 0) out[row] = s + blds[a];
        }
    } else {
        for (int row = gwave; row < B; row += nwav) {
            const f32x4* xr = reinterpret_cast<const f32x4*>(x) + (size_t)row * cvec;
            float s0 = 0.f, s1 = 0.f, s2 = 0.f, s3 = 0.f;
            #pragma unroll 4
            for (int j = lane; j < cvec; j += 64) {
                f32x4 xv = xr[j];
                s0 += dot4(xv, reinterpret_cast<const f32x4*>(Wlds + 0 * C)[j]);
                s1 += dot4(xv, reinterpret_cast<const f32x4*>(Wlds + 1 * C)[j]);
                s2 += dot4(xv, reinterpret_cast<const f32x4*>(Wlds + 2 * C)[j]);
                s3 += dot4(xv, reinterpret_cast<const f32x4*>(Wlds + 3 * C)[j]);
            }
            #pragma unroll
            for (int off = 32; off > 0; off >>= 1) {
                s0 += __shfl_down(s0, off, 64);
                s1 += __shfl_down(s1, off, 64);
                s2 += __shfl_down(s2, off, 64);
                s3 += __shfl_down(s3, off, 64);
            }
            if (lane == 0) {
                float m = s0 + blds[0];
                m = fmaxf(m, s1 + blds[1]);
                m = fmaxf(m, s2 + blds[2]);
                m = fmaxf(m, s3 + blds[3]);
                out[row] = m;
            }
        }
    }
}

extern "C" void kernel_launch(void* const* d_in, const int* in_sizes, int n_in,
                              void* d_out, int out_size, void* d_ws, size_t ws_size,
                              hipStream_t stream) {
    const float* x        = (const float*)d_in[0];
    const float* W        = (const float*)d_in[1];
    const float* bias     = (const float*)d_in[2];
    const int*   actions  = (const int*)d_in[3];
    const int*   is_glob  = (const int*)d_in[4];
    float* out            = (float*)d_out;

    const int B = in_sizes[3];            // actions count
    const int P = in_sizes[2];            // bias count
    const int C = in_sizes[0] / B;        // 1024

    // Memory-bound: cap grid at ~2048 blocks (32 waves/CU co-resident), grid-stride.
    int blocks = (B + WAVES_PER_BLOCK - 1) / WAVES_PER_BLOCK;
    if (blocks > 2048) blocks = 2048;

    ranker_kernel<<<blocks, BLOCK, 0, stream>>>(x, W, bias, actions, is_glob,
                                                out, B, C, P);
}